// Round 17
// baseline (7446.143 us; speedup 1.0000x reference)
//
#include <hip/hip_runtime.h>
#include <hip/hip_cooperative_groups.h>

namespace cg = cooperative_groups;

#define BB 256
#define SS 512
#define EE 512
#define HH 512
#define G4 2048
#define NTF 799

typedef __attribute__((ext_vector_type(8))) short bf16x8;
typedef __attribute__((ext_vector_type(4))) float f32x4;

#define MF(a, b, c) __builtin_amdgcn_mfma_f32_16x16x32_bf16((a), (b), (c), 0, 0, 0)

__device__ __forceinline__ float my_sig(float v) { return 1.0f / (1.0f + __expf(-v)); }
__device__ __forceinline__ float my_tanh(float v) { float e = __expf(2.0f * v); return 1.0f - 2.0f / (e + 1.0f); }

__device__ __forceinline__ unsigned short f2bf(float f) {   // RNE fp32->bf16
    unsigned u = __builtin_bit_cast(unsigned, f);
    u = (u + 0x7FFFu + ((u >> 16) & 1u)) >> 16;
    return (unsigned short)u;
}
__device__ __forceinline__ float bf2f(unsigned short h) {
    unsigned u = ((unsigned)h) << 16;
    return __builtin_bit_cast(float, u);
}
__device__ __forceinline__ unsigned packsplit(float f) {
    unsigned short hi = f2bf(f);
    unsigned short lo = f2bf(f - bf2f(hi));
    return ((unsigned)hi << 16) | (unsigned)lo;
}
__device__ __forceinline__ bf16x8 unhi(uint4 a, uint4 b) {
    union { unsigned u[4]; bf16x8 v; } r;
    r.u[0] = __builtin_amdgcn_perm(a.y, a.x, 0x07060302u);
    r.u[1] = __builtin_amdgcn_perm(a.w, a.z, 0x07060302u);
    r.u[2] = __builtin_amdgcn_perm(b.y, b.x, 0x07060302u);
    r.u[3] = __builtin_amdgcn_perm(b.w, b.z, 0x07060302u);
    return r.v;
}
__device__ __forceinline__ bf16x8 unlo(uint4 a, uint4 b) {
    union { unsigned u[4]; bf16x8 v; } r;
    r.u[0] = __builtin_amdgcn_perm(a.y, a.x, 0x05040100u);
    r.u[1] = __builtin_amdgcn_perm(a.w, a.z, 0x05040100u);
    r.u[2] = __builtin_amdgcn_perm(b.y, b.x, 0x05040100u);
    r.u[3] = __builtin_amdgcn_perm(b.w, b.z, 0x05040100u);
    return r.v;
}

// sc1 coherent / plain cached asm loads (verified r4-r15)
__device__ __forceinline__ void ld4_sc1(uint4& d, const unsigned* p) {
    asm volatile("global_load_dwordx4 %0, %1, off sc0 sc1" : "=v"(d) : "v"(p));
}
__device__ __forceinline__ void ld4_c(uint4& d, const unsigned* p) {
    asm volatile("global_load_dwordx4 %0, %1, off" : "=v"(d) : "v"(p));
}
__device__ __forceinline__ void st_devu(unsigned* p, unsigned v) {
    __hip_atomic_store(p, v, __ATOMIC_RELAXED, __HIP_MEMORY_SCOPE_AGENT);
}
__device__ __forceinline__ unsigned ld_devu(const unsigned* p) {
    return __hip_atomic_load(p, __ATOMIC_RELAXED, __HIP_MEMORY_SCOPE_AGENT);
}

// counted wait + scheduling fence (rule #18); vmcnt retires in issue order.
#define VMW(N)                                                                 \
    asm volatile("s_waitcnt vmcnt(" #N ")" ::: "memory");                      \
    __builtin_amdgcn_sched_barrier(0)

// ---------------------------------------------------------------------------
// Prep: split weights into bf16 hi/lo MFMA B-fragments (verbatim r8-r16).
// ---------------------------------------------------------------------------
__global__ void __launch_bounds__(256)
prep_split(const float* __restrict__ Wall, const float* __restrict__ Uall,
           const float* __restrict__ Wd,
           unsigned short* __restrict__ B1, unsigned short* __restrict__ B2)
{
    const int t = blockIdx.x * 256 + threadIdx.x;
    if (t < 262144) {
        const int lane = t & 63, wc = (t >> 6) & 3, kc = (t >> 8) & 31, cgi = t >> 13;
        const int kb = ((kc & 15) << 5) + ((lane >> 4) << 3);
        const int col = (wc << 9) + (cgi << 4) + (lane & 15);
        const float* src = (kc < 16) ? Wall : Uall;
        bf16x8 vh, vl;
#pragma unroll
        for (int j = 0; j < 8; ++j) {
            float f = src[(size_t)(kb + j) * G4 + col];
            unsigned short h16 = f2bf(f);
            vh[j] = (short)h16;
            vl[j] = (short)f2bf(f - bf2f(h16));
        }
        const int g = t >> 6;
        *(bf16x8*)(B1 + ((size_t)(g * 2 + 0) * 64 + lane) * 8) = vh;
        *(bf16x8*)(B1 + ((size_t)(g * 2 + 1) * 64 + lane) * 8) = vl;
    } else if (t < 262144 + 32768) {
        const int u = t - 262144;
        const int lane = u & 63, kch = (u >> 6) & 15, cgi = u >> 10;
        const int kb = (kch << 5) + ((lane >> 4) << 3);
        const int col = (cgi << 4) + (lane & 15);
        bf16x8 vh, vl;
#pragma unroll
        for (int j = 0; j < 8; ++j) {
            float f = Wd[(size_t)(kb + j) * HH + col];
            unsigned short h16 = f2bf(f);
            vh[j] = (short)h16;
            vl[j] = (short)f2bf(f - bf2f(h16));
        }
        const int g = u >> 6;
        *(bf16x8*)(B2 + ((size_t)(g * 2 + 0) * 64 + lane) * 8) = vh;
        *(bf16x8*)(B2 + ((size_t)(g * 2 + 1) * 64 + lane) * 8) = vl;
    }
}

// ---------------------------------------------------------------------------
// Prep: lay x out in packed MFMA A-fragment order:
// xfrag[(rg*512+s)*4+kq][fs=q*2+wr][lane][8] u32 (hi|lo). Wave kq reads its
// chunk as 64-lane x 32B contiguous (perfectly coalesced dwordx4 pairs).
// ---------------------------------------------------------------------------
__global__ void __launch_bounds__(256)
prep_xfrag(const float* __restrict__ x, unsigned* __restrict__ xf)
{
    const int b = blockIdx.x;          // rg*512 + s
    const int rg = b >> 9, s = b & 511;
    const int r0 = rg << 5;
    const int t = threadIdx.x;
    const int slot = t >> 3;           // 0..31 = kq*8 + q*2 + wr
    const int kq = slot >> 3;
    const int q  = (slot >> 1) & 3;
    const int wr = slot & 1;
    const int l0 = (t & 7) << 3;       // lane base (8 lanes per thread)
    unsigned* outp = xf + (((size_t)b * 4 + kq) * 8 + (q * 2 + wr)) * 512 + l0 * 8;
#pragma unroll
    for (int li = 0; li < 8; ++li) {
        const int lane = l0 + li;
        const int row = r0 + (wr << 4) + (lane & 15);
        const int kk = (kq << 7) + (q << 5) + ((lane >> 4) << 3);
        const float* src = x + (size_t)row * (SS * EE) + (size_t)s * EE + kk;
#pragma unroll
        for (int j = 0; j < 8; ++j)
            outp[li * 8 + j] = packsplit(src[j]);
    }
}

#define B1FRAG(kcv, wcv, term) (*(const bf16x8*)(B1 +                          \
    ((size_t)(((cgi * 32 + (kcv)) * 4 + (wcv)) * 2 + (term)) * 64 + lane) * 8))
#define B2FRAG(kchv, term) (*(const bf16x8*)(B2 +                              \
    ((size_t)((cgi * 16 + (kchv)) * 2 + (term)) * 64 + lane) * 8))

// gate-partial LDS index, bank-hashed (2-way max = free)
#define GPIDX(row, slot, col)                                                  \
    ((row) * 256 + (slot) * 64 + ((col) ^ (((((row) & 3) ^ (((row) >> 2) & 3))) << 4)))

// ---------------------------------------------------------------------------
// Persistent time-LSTM (r12 structure = 4.94ms verified). Change vs r12:
// phase A consumes x from fragment-order xfrag via coalesced per-lane loads
// (depth-2 VMW pipeline, r15-proven) -> no LDS staging, no drains, no syncs
// in phase A. Pre-barrier x.U MFMAs retained as the skew absorber (r16
// lesson: removing them regresses). Fallback = exact r12 staged path.
// ---------------------------------------------------------------------------
__global__ void __launch_bounds__(512) __attribute__((amdgpu_waves_per_eu(2)))
lstm_persistent(const float* __restrict__ x, const unsigned* __restrict__ xfrag,
                const int use_xf, const float* __restrict__ ts,
                const float* __restrict__ ball, const float* __restrict__ bu,
                const float* __restrict__ bd,
                const unsigned short* __restrict__ B1,
                const unsigned short* __restrict__ B2,
                unsigned* __restrict__ h2a, unsigned* __restrict__ h2b,
                unsigned* __restrict__ c2a, unsigned* __restrict__ c2b,
                float* __restrict__ hsum, float* __restrict__ tsT,
                unsigned* __restrict__ barv)
{
    cg::grid_group grid = cg::this_grid();
    const int tid = threadIdx.x;
    const int bid = blockIdx.x;
    const int gtid = (bid << 9) + tid;

    for (int i = gtid; i < BB * HH; i += 131072) { h2a[i] = 0u; c2a[i] = 0u; }
    for (int i = gtid; i < BB * SS; i += 131072) {
        int b = i >> 9, s = i & 511;
        tsT[s * BB + b] = ts[i];
    }
    if (gtid < 1024) barv[gtid] = 0u;
    grid.sync();

    // XCD-aware bijective relabeling (L2 affinity for the 4 cgi slices/XCD)
    const int xcd = bid & 7, tt = bid >> 3;
    const int cgi = (xcd << 2) | (tt & 3);   // 0..31 -> m0
    const int rg  = tt >> 2;                 // 0..7  -> r0 (sync group)
    const int r0  = rg << 5;
    const int m0  = cgi << 4;

    const int wid = tid >> 6, lane = tid & 63;
    const int lrow = lane & 15, lk8 = lane >> 4;
    const int kq = wid & 3, ch = wid >> 2;
    const int srow = tid >> 4, scb = tid & 15;
    const int rl = srow, mj = scb;

    __shared__ __align__(16) unsigned R1[32 * 512];  // AX(fallback) -> AC
    __shared__ __align__(16) unsigned R2[32 * 512];  // AH -> partials
    uint4* R1v = (uint4*)R1;
    uint4* R2v = (uint4*)R2;
    float* gp  = (float*)R2;              // [32][4][64] hashed, 32KB
    float* gp2 = (float*)(R2 + 8192);     // [32][132], 17KB

    unsigned* arr = barv;                 // per-rg counter at barv[rg*64]
    const int myline = rg << 6;

    // register-resident: W frags + Wd frags
    bf16x8 wfh[4][2], wfl[4][2], d2h[2], d2l[2];
#pragma unroll
    for (int q = 0; q < 4; ++q)
#pragma unroll
        for (int wcl = 0; wcl < 2; ++wcl) {
            wfh[q][wcl] = B1FRAG((kq << 2) + q, (ch << 1) + wcl, 0);
            wfl[q][wcl] = B1FRAG((kq << 2) + q, (ch << 1) + wcl, 1);
        }
#pragma unroll
    for (int e = 0; e < 2; ++e) {
        d2h[e] = B2FRAG((wid << 1) + e, 0);
        d2l[e] = B2FRAG((wid << 1) + e, 1);
    }

    float bias4[4];
#pragma unroll
    for (int k = 0; k < 4; ++k)
        bias4[k] = ball[(k << 9) + m0 + mj] + bu[(k << 9) + m0 + mj];
    const float bias2v = bd[m0 + mj];

    float creg = 0.f, hsreg = 0.f;

#pragma unroll 1
    for (int s = 0; s < SS; ++s) {
        const unsigned* h2p = (s & 1) ? h2b : h2a;
        const unsigned* c2p = (s & 1) ? c2b : c2a;
        unsigned* h2n = (s & 1) ? h2a : h2b;
        unsigned* c2n = (s & 1) ? c2a : c2b;
        const size_t sb = (size_t)s * EE;

        // ---- phase A: x.U MFMAs (pre-barrier skew absorber) ----
        f32x4 acc[2][2];
        acc[0][0] = acc[0][1] = acc[1][0] = acc[1][1] = (f32x4){0.f, 0.f, 0.f, 0.f};

        if (use_xf) {
            // fragment-order x: coalesced per-lane loads, depth-2 pipeline
            const unsigned* xf = xfrag + ((((size_t)rg * 512 + s) * 4 + kq) * 8) * 512
                                 + (lane << 3);
            uint4 xq[2][2][2];
            bf16x8 ufh[2][2], ufl[2][2];
#pragma unroll
            for (int wcl = 0; wcl < 2; ++wcl) {
                ufh[0][wcl] = B1FRAG(16 + (kq << 2), (ch << 1) + wcl, 0);
                ufl[0][wcl] = B1FRAG(16 + (kq << 2), (ch << 1) + wcl, 1);
            }
#define ISSUE_XF(B, Q)                                                         \
            ld4_c(xq[B][0][0], xf + ((Q) * 2 + 0) * 512);                      \
            ld4_c(xq[B][0][1], xf + ((Q) * 2 + 0) * 512 + 4);                  \
            ld4_c(xq[B][1][0], xf + ((Q) * 2 + 1) * 512);                      \
            ld4_c(xq[B][1][1], xf + ((Q) * 2 + 1) * 512 + 4);
#define PHA_Q(B, cur)                                                          \
            { _Pragma("unroll")                                                \
              for (int wr = 0; wr < 2; ++wr) {                                 \
                  bf16x8 ah = unhi(xq[B][wr][0], xq[B][wr][1]);                \
                  bf16x8 al = unlo(xq[B][wr][0], xq[B][wr][1]);                \
                  _Pragma("unroll")                                            \
                  for (int wcl = 0; wcl < 2; ++wcl) {                          \
                      acc[wr][wcl] = MF(ah, ufh[cur][wcl], acc[wr][wcl]);      \
                      acc[wr][wcl] = MF(ah, ufl[cur][wcl], acc[wr][wcl]);      \
                      acc[wr][wcl] = MF(al, ufh[cur][wcl], acc[wr][wcl]);      \
                  }                                                            \
              } }
            ISSUE_XF(0, 0); ISSUE_XF(1, 1);
#pragma unroll
            for (int q = 0; q < 4; ++q) {
                const int cur = q & 1;
                if (q < 3) {
#pragma unroll
                    for (int wcl = 0; wcl < 2; ++wcl) {
                        ufh[cur ^ 1][wcl] = B1FRAG(16 + (kq << 2) + q + 1, (ch << 1) + wcl, 0);
                        ufl[cur ^ 1][wcl] = B1FRAG(16 + (kq << 2) + q + 1, (ch << 1) + wcl, 1);
                    }
                    VMW(4);
                } else {
                    VMW(0);
                }
                if (q == 0) { PHA_Q(0, 0); ISSUE_XF(0, 2); }
                else if (q == 1) { PHA_Q(1, 1); ISSUE_XF(1, 3); }
                else if (q == 2) { PHA_Q(0, 0); }
                else { PHA_Q(1, 1); }
            }
        } else {
            // fallback: r12 staged path (packsplit from raw x)
            __syncthreads();
            const float* xfp = x + (size_t)(r0 + srow) * (SS * EE) + sb;
#pragma unroll
            for (int j = 0; j < 8; ++j) {
                const int ci = scb + (j << 4);
                float4 v = *(const float4*)(xfp + (ci << 2));
                uint4 pk;
                pk.x = packsplit(v.x); pk.y = packsplit(v.y);
                pk.z = packsplit(v.z); pk.w = packsplit(v.w);
                R1v[srow * 128 + (ci ^ (srow & 7))] = pk;
            }
            __syncthreads();
            bf16x8 ufh[2][2], ufl[2][2];
#pragma unroll
            for (int wcl = 0; wcl < 2; ++wcl) {
                ufh[0][wcl] = B1FRAG(16 + (kq << 2), (ch << 1) + wcl, 0);
                ufl[0][wcl] = B1FRAG(16 + (kq << 2), (ch << 1) + wcl, 1);
            }
#pragma unroll
            for (int q = 0; q < 4; ++q) {
                const int cur = q & 1, nxt = cur ^ 1;
                if (q < 3) {
#pragma unroll
                    for (int wcl = 0; wcl < 2; ++wcl) {
                        ufh[nxt][wcl] = B1FRAG(16 + (kq << 2) + q + 1, (ch << 1) + wcl, 0);
                        ufl[nxt][wcl] = B1FRAG(16 + (kq << 2) + q + 1, (ch << 1) + wcl, 1);
                    }
                }
                const int kcp = (kq << 2) + q;
#pragma unroll
                for (int wr = 0; wr < 2; ++wr) {
                    const int row_ = (wr << 4) | lrow;
                    const int cb_  = (kcp << 3) + (lk8 << 1);
                    uint4 qa = R1v[row_ * 128 + (cb_ ^ (row_ & 7))];
                    uint4 qb = R1v[row_ * 128 + ((cb_ + 1) ^ (row_ & 7))];
                    bf16x8 ah = unhi(qa, qb), al = unlo(qa, qb);
#pragma unroll
                    for (int wcl = 0; wcl < 2; ++wcl) {
                        acc[wr][wcl] = MF(ah, ufh[cur][wcl], acc[wr][wcl]);
                        acc[wr][wcl] = MF(ah, ufl[cur][wcl], acc[wr][wcl]);
                        acc[wr][wcl] = MF(al, ufh[cur][wcl], acc[wr][wcl]);
                    }
                }
            }
        }

        // ---- B: per-rg wait (all 32 same-rg blocks finished step s-1) ----
        if (tid == 0) {
            const unsigned tgt = 32u * (unsigned)s;
            while (ld_devu(&arr[myline]) < tgt)
                __builtin_amdgcn_s_sleep(4);
        }
        __syncthreads();
        asm volatile("" ::: "memory");

        // ---- C: fused h+c load (16 dwordx4, vmcnt(8)/vmcnt(0) split) ----
        {
            const unsigned* hp = h2p + (r0 + srow) * HH;
            const unsigned* cp = c2p + (r0 + srow) * HH;
            uint4 hv[8], cv[8];
#pragma unroll
            for (int j = 0; j < 8; ++j) ld4_sc1(hv[j], hp + ((scb + (j << 4)) << 2));
#pragma unroll
            for (int j = 0; j < 8; ++j) ld4_sc1(cv[j], cp + ((scb + (j << 4)) << 2));
            asm volatile("s_waitcnt vmcnt(8)" ::: "memory");
            __builtin_amdgcn_sched_barrier(0);
#pragma unroll
            for (int j = 0; j < 8; ++j) {
                const int ci = scb + (j << 4);
                R2v[srow * 128 + (ci ^ (srow & 7))] = hv[j];
            }
            asm volatile("s_waitcnt vmcnt(0)" ::: "memory");
            __builtin_amdgcn_sched_barrier(0);
#pragma unroll
            for (int j = 0; j < 8; ++j) {
                const int ci = scb + (j << 4);
                R1v[srow * 128 + (ci ^ (srow & 7))] = cv[j];
            }
        }
        __syncthreads();

        // ---- phase B: h.W MFMAs into acc; then G2 (c.Wd) ----
#pragma unroll
        for (int q = 0; q < 4; ++q) {
            const int kcp = (kq << 2) + q;
#pragma unroll
            for (int wr = 0; wr < 2; ++wr) {
                const int row_ = (wr << 4) | lrow;
                const int cb_  = (kcp << 3) + (lk8 << 1);
                uint4 qa = R2v[row_ * 128 + (cb_ ^ (row_ & 7))];
                uint4 qb = R2v[row_ * 128 + ((cb_ + 1) ^ (row_ & 7))];
                bf16x8 ah = unhi(qa, qb), al = unlo(qa, qb);
#pragma unroll
                for (int wcl = 0; wcl < 2; ++wcl) {
                    acc[wr][wcl] = MF(ah, wfh[q][wcl], acc[wr][wcl]);
                    acc[wr][wcl] = MF(ah, wfl[q][wcl], acc[wr][wcl]);
                    acc[wr][wcl] = MF(al, wfh[q][wcl], acc[wr][wcl]);
                }
            }
        }
        f32x4 acc2[2];
        acc2[0] = (f32x4){0.f, 0.f, 0.f, 0.f};
        acc2[1] = (f32x4){0.f, 0.f, 0.f, 0.f};
#pragma unroll
        for (int e = 0; e < 2; ++e) {
            const int kch = (wid << 1) + e;
#pragma unroll
            for (int wr = 0; wr < 2; ++wr) {
                const int row_ = (wr << 4) | lrow;
                const int cb_  = (kch << 3) + (lk8 << 1);
                uint4 qa = R1v[row_ * 128 + (cb_ ^ (row_ & 7))];
                uint4 qb = R1v[row_ * 128 + ((cb_ + 1) ^ (row_ & 7))];
                bf16x8 ah = unhi(qa, qb), al = unlo(qa, qb);
                acc2[wr] = MF(ah, d2h[e], acc2[wr]);
                acc2[wr] = MF(ah, d2l[e], acc2[wr]);
                acc2[wr] = MF(al, d2h[e], acc2[wr]);
            }
        }
        __syncthreads();   // AH/AC reads done before partials overwrite R2

        // ---- E: partial writes (gp: slot=kq; gp2: slot=wid) ----
#pragma unroll
        for (int wr = 0; wr < 2; ++wr)
#pragma unroll
            for (int wcl = 0; wcl < 2; ++wcl)
#pragma unroll
                for (int i = 0; i < 4; ++i)
                    gp[GPIDX((wr << 4) + (lk8 << 2) + i, kq, ((ch << 1) + wcl) * 16 + lrow)] = acc[wr][wcl][i];
#pragma unroll
        for (int wr = 0; wr < 2; ++wr)
#pragma unroll
            for (int i = 0; i < 4; ++i)
                gp2[((wr << 4) + (lk8 << 2) + i) * 132 + (wid << 4) + lrow] = acc2[wr][i];
        __syncthreads();

        // ---- F: reduce + update + sc1 stores ----
        {
            float gv[4];
#pragma unroll
            for (int k = 0; k < 4; ++k) {
                float sacc = bias4[k];
#pragma unroll
                for (int p = 0; p < 4; ++p)
                    sacc += gp[GPIDX(rl, p, (k << 4) + mj)];
                gv[k] = my_sig(sacc);
            }
            float sacc2 = bias2v;
#pragma unroll
            for (int p = 0; p < 8; ++p)
                sacc2 += gp2[rl * 132 + (p << 4) + mj];
            const float cs1v = my_tanh(sacc2);
            const float tv = tsT[s * BB + r0 + rl];
            const float cadj = creg + cs1v * (tv - 1.0f);
            const float cnew = gv[0] * cadj + gv[1] * gv[3];
            const float hnew = gv[2] * my_tanh(cnew);
            creg = cnew; hsreg += hnew;
            const int gidx = (r0 + rl) * HH + m0 + mj;
            st_devu(&c2n[gidx], packsplit(cnew));
            st_devu(&h2n[gidx], packsplit(hnew));
        }

        // ---- G: drain + per-rg arrival ----
        asm volatile("s_waitcnt vmcnt(0)" ::: "memory");
        __syncthreads();
        if (tid == 0)
            __hip_atomic_fetch_add(&arr[myline], 1u, __ATOMIC_RELAXED,
                                   __HIP_MEMORY_SCOPE_AGENT);
    }

    hsum[(r0 + rl) * HH + m0 + mj] = hsreg;
}

// Tail: sub = relu(tfidf@fcw+b); x = [sub | hsum/512]; 3-layer MLP (fp32).
__global__ void __launch_bounds__(256)
tail_kernel(const float* __restrict__ tfidf, const float* __restrict__ hsum,
            const float* __restrict__ fcw, const float* __restrict__ fcb,
            const float* __restrict__ l1w, const float* __restrict__ l1b,
            const float* __restrict__ l2w, const float* __restrict__ l2b,
            const float* __restrict__ low, const float* __restrict__ lob,
            float* __restrict__ out)
{
    const int row = blockIdx.x;
    const int t = threadIdx.x;
    __shared__ float tf[800];
    __shared__ float xrow[1024];
    __shared__ float y1[256];
    __shared__ float y2[128];

    for (int k = t; k < NTF; k += 256) tf[k] = tfidf[row * NTF + k];
    __syncthreads();

    for (int n = t; n < 512; n += 256) {
        float acc = fcb[n];
        for (int k = 0; k < NTF; ++k) acc += tf[k] * fcw[k * 512 + n];
        xrow[n] = fmaxf(acc, 0.f);
    }
    for (int n = t; n < 512; n += 256)
        xrow[512 + n] = hsum[row * HH + n] * (1.0f / 512.0f);
    __syncthreads();

    {
        float acc = l1b[t];
        for (int k = 0; k < 1024; ++k) acc += xrow[k] * l1w[k * 256 + t];
        y1[t] = fmaxf(acc, 0.f);
    }
    __syncthreads();
    if (t < 128) {
        float acc = l2b[t];
        for (int k = 0; k < 256; ++k) acc += y1[k] * l2w[k * 128 + t];
        y2[t] = fmaxf(acc, 0.f);
    }
    __syncthreads();
    if (t < 2) {
        float acc = lob[t];
        for (int k = 0; k < 128; ++k) acc += y2[k] * low[k * 2 + t];
        out[row * 2 + t] = acc;
    }
}

extern "C" void kernel_launch(void* const* d_in, const int* in_sizes, int n_in,
                              void* d_out, int out_size, void* d_ws, size_t ws_size,
                              hipStream_t stream)
{
    const float* x     = (const float*)d_in[0];
    const float* ts    = (const float*)d_in[1];
    const float* tfidf = (const float*)d_in[2];
    const float* Wall  = (const float*)d_in[3];
    const float* ball  = (const float*)d_in[4];
    const float* Uall  = (const float*)d_in[5];
    const float* bu    = (const float*)d_in[6];
    const float* Wd    = (const float*)d_in[7];
    const float* bd    = (const float*)d_in[8];
    const float* fcw   = (const float*)d_in[9];
    const float* fcb   = (const float*)d_in[10];
    const float* l1w   = (const float*)d_in[11];
    const float* l1b   = (const float*)d_in[12];
    const float* l2w   = (const float*)d_in[13];
    const float* l2b   = (const float*)d_in[14];
    const float* low   = (const float*)d_in[15];
    const float* lob   = (const float*)d_in[16];
    float* out = (float*)d_out;

    unsigned* wsu = (unsigned*)d_ws;
    unsigned* h2a = wsu;
    unsigned* h2b = h2a + BB * HH;
    unsigned* c2a = h2b + BB * HH;
    unsigned* c2b = c2a + BB * HH;
    float* hs  = (float*)(c2b + BB * HH);
    float* tsT = hs + BB * HH;
    unsigned* barv = (unsigned*)(tsT + BB * SS);                  // 1024 u32
    unsigned short* B1 = (unsigned short*)(barv + 1024);
    unsigned short* B2 = B1 + (size_t)32 * 32 * 4 * 2 * 64 * 8;   // B1 = 8.4MB
    unsigned* xfrag = (unsigned*)(B2 + (size_t)32 * 16 * 2 * 64 * 8);
    // xfrag = 8rg * 512s * 4kq * 8slots * 512 u32 = 268MB
    const size_t need_xf = ((char*)(xfrag + (size_t)8 * 512 * 4 * 8 * 512)) - (char*)d_ws;
    const int use_xf = (ws_size >= need_xf) ? 1 : 0;

    prep_split<<<1152, 256, 0, stream>>>(Wall, Uall, Wd, B1, B2);
    if (use_xf)
        prep_xfrag<<<4096, 256, 0, stream>>>(x, xfrag);

    void* args[] = { (void*)&x, (void*)&xfrag, (void*)&use_xf, (void*)&ts,
                     (void*)&ball, (void*)&bu, (void*)&bd,
                     (void*)&B1, (void*)&B2,
                     (void*)&h2a, (void*)&h2b, (void*)&c2a, (void*)&c2b,
                     (void*)&hs, (void*)&tsT, (void*)&barv };
    hipLaunchCooperativeKernel((void*)lstm_persistent, dim3(256), dim3(512), args, 0, stream);

    tail_kernel<<<256, 256, 0, stream>>>(tfidf, hs, fcw, fcb, l1w, l1b, l2w, l2b,
                                         low, lob, out);
}

// Round 18
// 4980.629 us; speedup vs baseline: 1.4950x; 1.4950x over previous
//
#include <hip/hip_runtime.h>
#include <hip/hip_cooperative_groups.h>

namespace cg = cooperative_groups;

#define BB 256
#define SS 512
#define EE 512
#define HH 512
#define G4 2048
#define NTF 799

typedef __attribute__((ext_vector_type(8))) short bf16x8;
typedef __attribute__((ext_vector_type(4))) float f32x4;

#define MF(a, b, c) __builtin_amdgcn_mfma_f32_16x16x32_bf16((a), (b), (c), 0, 0, 0)

__device__ __forceinline__ float my_sig(float v) { return 1.0f / (1.0f + __expf(-v)); }
__device__ __forceinline__ float my_tanh(float v) { float e = __expf(2.0f * v); return 1.0f - 2.0f / (e + 1.0f); }

__device__ __forceinline__ unsigned short f2bf(float f) {   // RNE fp32->bf16
    unsigned u = __builtin_bit_cast(unsigned, f);
    u = (u + 0x7FFFu + ((u >> 16) & 1u)) >> 16;
    return (unsigned short)u;
}
__device__ __forceinline__ float bf2f(unsigned short h) {
    unsigned u = ((unsigned)h) << 16;
    return __builtin_bit_cast(float, u);
}
__device__ __forceinline__ unsigned packsplit(float f) {
    unsigned short hi = f2bf(f);
    unsigned short lo = f2bf(f - bf2f(hi));
    return ((unsigned)hi << 16) | (unsigned)lo;
}
__device__ __forceinline__ bf16x8 unhi(uint4 a, uint4 b) {
    union { unsigned u[4]; bf16x8 v; } r;
    r.u[0] = __builtin_amdgcn_perm(a.y, a.x, 0x07060302u);
    r.u[1] = __builtin_amdgcn_perm(a.w, a.z, 0x07060302u);
    r.u[2] = __builtin_amdgcn_perm(b.y, b.x, 0x07060302u);
    r.u[3] = __builtin_amdgcn_perm(b.w, b.z, 0x07060302u);
    return r.v;
}
__device__ __forceinline__ bf16x8 unlo(uint4 a, uint4 b) {
    union { unsigned u[4]; bf16x8 v; } r;
    r.u[0] = __builtin_amdgcn_perm(a.y, a.x, 0x05040100u);
    r.u[1] = __builtin_amdgcn_perm(a.w, a.z, 0x05040100u);
    r.u[2] = __builtin_amdgcn_perm(b.y, b.x, 0x05040100u);
    r.u[3] = __builtin_amdgcn_perm(b.w, b.z, 0x05040100u);
    return r.v;
}

// sc1 coherent / plain cached asm loads (verified r4-r12)
__device__ __forceinline__ void ld4_sc1(uint4& d, const unsigned* p) {
    asm volatile("global_load_dwordx4 %0, %1, off sc0 sc1" : "=v"(d) : "v"(p));
}
// PLAIN CACHED (r18 change): xpk slices allocate in L2+L3 -> 7 of 8 XCDs hit
// L3 instead of HBM. r12's `nt` here marked lines no-allocate in L2/L3, which
// forced EVERY XCD's x read to HBM (FETCH 3.5GB ~= 14x of xpk) inside the
// serial step. nt was the bug, not the protection.
__device__ __forceinline__ void ld4_c(uint4& d, const unsigned* p) {
    asm volatile("global_load_dwordx4 %0, %1, off" : "=v"(d) : "v"(p));
}
__device__ __forceinline__ void st_devu(unsigned* p, unsigned v) {
    __hip_atomic_store(p, v, __ATOMIC_RELAXED, __HIP_MEMORY_SCOPE_AGENT);
}
__device__ __forceinline__ unsigned ld_devu(const unsigned* p) {
    return __hip_atomic_load(p, __ATOMIC_RELAXED, __HIP_MEMORY_SCOPE_AGENT);
}

// ---------------------------------------------------------------------------
// Prep: split weights into bf16 hi/lo MFMA B-fragments (verbatim r8-r12).
// ---------------------------------------------------------------------------
__global__ void __launch_bounds__(256)
prep_split(const float* __restrict__ Wall, const float* __restrict__ Uall,
           const float* __restrict__ Wd,
           unsigned short* __restrict__ B1, unsigned short* __restrict__ B2)
{
    const int t = blockIdx.x * 256 + threadIdx.x;
    if (t < 262144) {
        const int lane = t & 63, wc = (t >> 6) & 3, kc = (t >> 8) & 31, cgi = t >> 13;
        const int kb = ((kc & 15) << 5) + ((lane >> 4) << 3);
        const int col = (wc << 9) + (cgi << 4) + (lane & 15);
        const float* src = (kc < 16) ? Wall : Uall;
        bf16x8 vh, vl;
#pragma unroll
        for (int j = 0; j < 8; ++j) {
            float f = src[(size_t)(kb + j) * G4 + col];
            unsigned short h16 = f2bf(f);
            vh[j] = (short)h16;
            vl[j] = (short)f2bf(f - bf2f(h16));
        }
        const int g = t >> 6;
        *(bf16x8*)(B1 + ((size_t)(g * 2 + 0) * 64 + lane) * 8) = vh;
        *(bf16x8*)(B1 + ((size_t)(g * 2 + 1) * 64 + lane) * 8) = vl;
    } else if (t < 262144 + 32768) {
        const int u = t - 262144;
        const int lane = u & 63, kch = (u >> 6) & 15, cgi = u >> 10;
        const int kb = (kch << 5) + ((lane >> 4) << 3);
        const int col = (cgi << 4) + (lane & 15);
        bf16x8 vh, vl;
#pragma unroll
        for (int j = 0; j < 8; ++j) {
            float f = Wd[(size_t)(kb + j) * HH + col];
            unsigned short h16 = f2bf(f);
            vh[j] = (short)h16;
            vl[j] = (short)f2bf(f - bf2f(h16));
        }
        const int g = u >> 6;
        *(bf16x8*)(B2 + ((size_t)(g * 2 + 0) * 64 + lane) * 8) = vh;
        *(bf16x8*)(B2 + ((size_t)(g * 2 + 1) * 64 + lane) * 8) = vl;
    }
}

// Prep: pack x -> hi|lo u32 (same layout) so step staging is a pure copy.
__global__ void __launch_bounds__(256)
prep_pack(const float* __restrict__ x, unsigned* __restrict__ xpk)
{
    const size_t i = (size_t)blockIdx.x * 256 + threadIdx.x;   // 16.7M float4s
    float4 v = ((const float4*)x)[i];
    uint4 p;
    p.x = packsplit(v.x); p.y = packsplit(v.y);
    p.z = packsplit(v.z); p.w = packsplit(v.w);
    ((uint4*)xpk)[i] = p;
}

#define B1FRAG(kcv, wcv, term) (*(const bf16x8*)(B1 +                          \
    ((size_t)(((cgi * 32 + (kcv)) * 4 + (wcv)) * 2 + (term)) * 64 + lane) * 8))
#define B2FRAG(kchv, term) (*(const bf16x8*)(B2 +                              \
    ((size_t)((cgi * 16 + (kchv)) * 2 + (term)) * 64 + lane) * 8))

// gate-partial LDS index, bank-hashed (2-way max = free)
#define GPIDX(row, slot, col)                                                  \
    ((row) * 256 + (slot) * 64 + ((col) ^ (((((row) & 3) ^ (((row) >> 2) & 3))) << 4)))

// ---------------------------------------------------------------------------
// Persistent time-LSTM: r12 structure VERBATIM (4.94ms verified) with exactly
// one change: xpk staging loads are plain cached (ld4_c) instead of nt.
// Wave (kq, ch): K-window kq*128, gate-col half ch*32. W/Wd frags register-
// resident; U streamed from XCD-local L2 (double-buffered under phase-A
// MFMAs, the skew absorber). Sync = per-rg counter (32 blocks).
// ---------------------------------------------------------------------------
__global__ void __launch_bounds__(512) __attribute__((amdgpu_waves_per_eu(2)))
lstm_persistent(const float* __restrict__ x, const unsigned* __restrict__ xp,
                const int use_xp, const float* __restrict__ ts,
                const float* __restrict__ ball, const float* __restrict__ bu,
                const float* __restrict__ bd,
                const unsigned short* __restrict__ B1,
                const unsigned short* __restrict__ B2,
                unsigned* __restrict__ h2a, unsigned* __restrict__ h2b,
                unsigned* __restrict__ c2a, unsigned* __restrict__ c2b,
                float* __restrict__ hsum, float* __restrict__ tsT,
                unsigned* __restrict__ barv)
{
    cg::grid_group grid = cg::this_grid();
    const int tid = threadIdx.x;
    const int bid = blockIdx.x;
    const int gtid = (bid << 9) + tid;

    for (int i = gtid; i < BB * HH; i += 131072) { h2a[i] = 0u; c2a[i] = 0u; }
    for (int i = gtid; i < BB * SS; i += 131072) {
        int b = i >> 9, s = i & 511;
        tsT[s * BB + b] = ts[i];
    }
    if (gtid < 1024) barv[gtid] = 0u;
    grid.sync();

    // XCD-aware bijective relabeling (L2 affinity for the 4 cgi slices/XCD)
    const int xcd = bid & 7, tt = bid >> 3;
    const int cgi = (xcd << 2) | (tt & 3);   // 0..31 -> m0
    const int rg  = tt >> 2;                 // 0..7  -> r0 (sync group)
    const int r0  = rg << 5;
    const int m0  = cgi << 4;

    const int wid = tid >> 6, lane = tid & 63;
    const int lrow = lane & 15, lk8 = lane >> 4;
    const int kq = wid & 3, ch = wid >> 2;
    const int srow = tid >> 4, scb = tid & 15;
    const int rl = srow, mj = scb;

    __shared__ __align__(16) unsigned R1[32 * 512];  // AX -> AC
    __shared__ __align__(16) unsigned R2[32 * 512];  // AH -> partials
    uint4* R1v = (uint4*)R1;
    uint4* R2v = (uint4*)R2;
    float* gp  = (float*)R2;              // [32][4][64] hashed, 32KB
    float* gp2 = (float*)(R2 + 8192);     // [32][132], 17KB

    unsigned* arr = barv;                 // per-rg counter at barv[rg*64]
    const int myline = rg << 6;

    // register-resident: W frags + Wd frags
    bf16x8 wfh[4][2], wfl[4][2], d2h[2], d2l[2];
#pragma unroll
    for (int q = 0; q < 4; ++q)
#pragma unroll
        for (int wcl = 0; wcl < 2; ++wcl) {
            wfh[q][wcl] = B1FRAG((kq << 2) + q, (ch << 1) + wcl, 0);
            wfl[q][wcl] = B1FRAG((kq << 2) + q, (ch << 1) + wcl, 1);
        }
#pragma unroll
    for (int e = 0; e < 2; ++e) {
        d2h[e] = B2FRAG((wid << 1) + e, 0);
        d2l[e] = B2FRAG((wid << 1) + e, 1);
    }

    float bias4[4];
#pragma unroll
    for (int k = 0; k < 4; ++k)
        bias4[k] = ball[(k << 9) + m0 + mj] + bu[(k << 9) + m0 + mj];
    const float bias2v = bd[m0 + mj];

    float creg = 0.f, hsreg = 0.f;

#pragma unroll 1
    for (int s = 0; s < SS; ++s) {
        const unsigned* h2p = (s & 1) ? h2b : h2a;
        const unsigned* c2p = (s & 1) ? c2b : c2a;
        unsigned* h2n = (s & 1) ? h2a : h2b;
        unsigned* c2n = (s & 1) ? c2a : c2b;
        const size_t sb = (size_t)s * EE;

        // ---- A: stage AX <- x(s) (plain cached loads: L3-shared slices) ----
        __syncthreads();                      // prev-step partial reads done
        if (use_xp) {
            const unsigned* xpp = xp + (size_t)(r0 + srow) * (SS * EE) + sb;
            uint4 xv[8];
#pragma unroll
            for (int j = 0; j < 8; ++j) ld4_c(xv[j], xpp + ((scb + (j << 4)) << 2));
            asm volatile("s_waitcnt vmcnt(0)" ::: "memory");
            __builtin_amdgcn_sched_barrier(0);
#pragma unroll
            for (int j = 0; j < 8; ++j) {
                const int ci = scb + (j << 4);
                R1v[srow * 128 + (ci ^ (srow & 7))] = xv[j];
            }
        } else {
            const float* xfp = x + (size_t)(r0 + srow) * (SS * EE) + sb;
#pragma unroll
            for (int j = 0; j < 8; ++j) {
                const int ci = scb + (j << 4);
                float4 v = *(const float4*)(xfp + (ci << 2));
                uint4 pk;
                pk.x = packsplit(v.x); pk.y = packsplit(v.y);
                pk.z = packsplit(v.z); pk.w = packsplit(v.w);
                R1v[srow * 128 + (ci ^ (srow & 7))] = pk;
            }
        }
        __syncthreads();

        // ---- phase A: x.U MFMAs, U frags streamed (double-buffered) ----
        f32x4 acc[2][2];
        acc[0][0] = acc[0][1] = acc[1][0] = acc[1][1] = (f32x4){0.f, 0.f, 0.f, 0.f};
        {
            bf16x8 ufh[2][2], ufl[2][2];
#pragma unroll
            for (int wcl = 0; wcl < 2; ++wcl) {
                ufh[0][wcl] = B1FRAG(16 + (kq << 2), (ch << 1) + wcl, 0);
                ufl[0][wcl] = B1FRAG(16 + (kq << 2), (ch << 1) + wcl, 1);
            }
#pragma unroll
            for (int q = 0; q < 4; ++q) {
                const int cur = q & 1, nxt = cur ^ 1;
                if (q < 3) {
#pragma unroll
                    for (int wcl = 0; wcl < 2; ++wcl) {
                        ufh[nxt][wcl] = B1FRAG(16 + (kq << 2) + q + 1, (ch << 1) + wcl, 0);
                        ufl[nxt][wcl] = B1FRAG(16 + (kq << 2) + q + 1, (ch << 1) + wcl, 1);
                    }
                }
                const int kcp = (kq << 2) + q;
#pragma unroll
                for (int wr = 0; wr < 2; ++wr) {
                    const int row_ = (wr << 4) | lrow;
                    const int cb_  = (kcp << 3) + (lk8 << 1);
                    uint4 qa = R1v[row_ * 128 + (cb_ ^ (row_ & 7))];
                    uint4 qb = R1v[row_ * 128 + ((cb_ + 1) ^ (row_ & 7))];
                    bf16x8 ah = unhi(qa, qb), al = unlo(qa, qb);
#pragma unroll
                    for (int wcl = 0; wcl < 2; ++wcl) {
                        acc[wr][wcl] = MF(ah, ufh[cur][wcl], acc[wr][wcl]);
                        acc[wr][wcl] = MF(ah, ufl[cur][wcl], acc[wr][wcl]);
                        acc[wr][wcl] = MF(al, ufh[cur][wcl], acc[wr][wcl]);
                    }
                }
            }
        }

        // ---- B: per-rg wait (all 32 same-rg blocks finished step s-1) ----
        if (tid == 0) {
            const unsigned tgt = 32u * (unsigned)s;
            while (ld_devu(&arr[myline]) < tgt)
                __builtin_amdgcn_s_sleep(4);
        }
        __syncthreads();
        asm volatile("" ::: "memory");

        // ---- C: fused h+c load (16 dwordx4, vmcnt(8)/vmcnt(0) split) ----
        {
            const unsigned* hp = h2p + (r0 + srow) * HH;
            const unsigned* cp = c2p + (r0 + srow) * HH;
            uint4 hv[8], cv[8];
#pragma unroll
            for (int j = 0; j < 8; ++j) ld4_sc1(hv[j], hp + ((scb + (j << 4)) << 2));
#pragma unroll
            for (int j = 0; j < 8; ++j) ld4_sc1(cv[j], cp + ((scb + (j << 4)) << 2));
            asm volatile("s_waitcnt vmcnt(8)" ::: "memory");
            __builtin_amdgcn_sched_barrier(0);
#pragma unroll
            for (int j = 0; j < 8; ++j) {
                const int ci = scb + (j << 4);
                R2v[srow * 128 + (ci ^ (srow & 7))] = hv[j];
            }
            asm volatile("s_waitcnt vmcnt(0)" ::: "memory");
            __builtin_amdgcn_sched_barrier(0);
#pragma unroll
            for (int j = 0; j < 8; ++j) {
                const int ci = scb + (j << 4);
                R1v[srow * 128 + (ci ^ (srow & 7))] = cv[j];
            }
        }
        __syncthreads();

        // ---- phase B: h.W MFMAs (resident frags) into same acc; then G2 ----
#pragma unroll
        for (int q = 0; q < 4; ++q) {
            const int kcp = (kq << 2) + q;
#pragma unroll
            for (int wr = 0; wr < 2; ++wr) {
                const int row_ = (wr << 4) | lrow;
                const int cb_  = (kcp << 3) + (lk8 << 1);
                uint4 qa = R2v[row_ * 128 + (cb_ ^ (row_ & 7))];
                uint4 qb = R2v[row_ * 128 + ((cb_ + 1) ^ (row_ & 7))];
                bf16x8 ah = unhi(qa, qb), al = unlo(qa, qb);
#pragma unroll
                for (int wcl = 0; wcl < 2; ++wcl) {
                    acc[wr][wcl] = MF(ah, wfh[q][wcl], acc[wr][wcl]);
                    acc[wr][wcl] = MF(ah, wfl[q][wcl], acc[wr][wcl]);
                    acc[wr][wcl] = MF(al, wfh[q][wcl], acc[wr][wcl]);
                }
            }
        }
        f32x4 acc2[2];
        acc2[0] = (f32x4){0.f, 0.f, 0.f, 0.f};
        acc2[1] = (f32x4){0.f, 0.f, 0.f, 0.f};
#pragma unroll
        for (int e = 0; e < 2; ++e) {
            const int kch = (wid << 1) + e;
#pragma unroll
            for (int wr = 0; wr < 2; ++wr) {
                const int row_ = (wr << 4) | lrow;
                const int cb_  = (kch << 3) + (lk8 << 1);
                uint4 qa = R1v[row_ * 128 + (cb_ ^ (row_ & 7))];
                uint4 qb = R1v[row_ * 128 + ((cb_ + 1) ^ (row_ & 7))];
                bf16x8 ah = unhi(qa, qb), al = unlo(qa, qb);
                acc2[wr] = MF(ah, d2h[e], acc2[wr]);
                acc2[wr] = MF(ah, d2l[e], acc2[wr]);
                acc2[wr] = MF(al, d2h[e], acc2[wr]);
            }
        }
        __syncthreads();   // AH/AC reads done before partials overwrite R2

        // ---- E: partial writes (gp: slot=kq; gp2: slot=wid) ----
#pragma unroll
        for (int wr = 0; wr < 2; ++wr)
#pragma unroll
            for (int wcl = 0; wcl < 2; ++wcl)
#pragma unroll
                for (int i = 0; i < 4; ++i)
                    gp[GPIDX((wr << 4) + (lk8 << 2) + i, kq, ((ch << 1) + wcl) * 16 + lrow)] = acc[wr][wcl][i];
#pragma unroll
        for (int wr = 0; wr < 2; ++wr)
#pragma unroll
            for (int i = 0; i < 4; ++i)
                gp2[((wr << 4) + (lk8 << 2) + i) * 132 + (wid << 4) + lrow] = acc2[wr][i];
        __syncthreads();

        // ---- F: reduce + update + sc1 stores ----
        {
            float gv[4];
#pragma unroll
            for (int k = 0; k < 4; ++k) {
                float sacc = bias4[k];
#pragma unroll
                for (int p = 0; p < 4; ++p)
                    sacc += gp[GPIDX(rl, p, (k << 4) + mj)];
                gv[k] = my_sig(sacc);
            }
            float sacc2 = bias2v;
#pragma unroll
            for (int p = 0; p < 8; ++p)
                sacc2 += gp2[rl * 132 + (p << 4) + mj];
            const float cs1v = my_tanh(sacc2);
            const float tv = tsT[s * BB + r0 + rl];
            const float cadj = creg + cs1v * (tv - 1.0f);
            const float cnew = gv[0] * cadj + gv[1] * gv[3];
            const float hnew = gv[2] * my_tanh(cnew);
            creg = cnew; hsreg += hnew;
            const int gidx = (r0 + rl) * HH + m0 + mj;
            st_devu(&c2n[gidx], packsplit(cnew));
            st_devu(&h2n[gidx], packsplit(hnew));
        }

        // ---- G: drain + per-rg arrival ----
        asm volatile("s_waitcnt vmcnt(0)" ::: "memory");
        __syncthreads();
        if (tid == 0)
            __hip_atomic_fetch_add(&arr[myline], 1u, __ATOMIC_RELAXED,
                                   __HIP_MEMORY_SCOPE_AGENT);
    }

    hsum[(r0 + rl) * HH + m0 + mj] = hsreg;
}

// Tail: sub = relu(tfidf@fcw+b); x = [sub | hsum/512]; 3-layer MLP (fp32).
__global__ void __launch_bounds__(256)
tail_kernel(const float* __restrict__ tfidf, const float* __restrict__ hsum,
            const float* __restrict__ fcw, const float* __restrict__ fcb,
            const float* __restrict__ l1w, const float* __restrict__ l1b,
            const float* __restrict__ l2w, const float* __restrict__ l2b,
            const float* __restrict__ low, const float* __restrict__ lob,
            float* __restrict__ out)
{
    const int row = blockIdx.x;
    const int t = threadIdx.x;
    __shared__ float tf[800];
    __shared__ float xrow[1024];
    __shared__ float y1[256];
    __shared__ float y2[128];

    for (int k = t; k < NTF; k += 256) tf[k] = tfidf[row * NTF + k];
    __syncthreads();

    for (int n = t; n < 512; n += 256) {
        float acc = fcb[n];
        for (int k = 0; k < NTF; ++k) acc += tf[k] * fcw[k * 512 + n];
        xrow[n] = fmaxf(acc, 0.f);
    }
    for (int n = t; n < 512; n += 256)
        xrow[512 + n] = hsum[row * HH + n] * (1.0f / 512.0f);
    __syncthreads();

    {
        float acc = l1b[t];
        for (int k = 0; k < 1024; ++k) acc += xrow[k] * l1w[k * 256 + t];
        y1[t] = fmaxf(acc, 0.f);
    }
    __syncthreads();
    if (t < 128) {
        float acc = l2b[t];
        for (int k = 0; k < 256; ++k) acc += y1[k] * l2w[k * 128 + t];
        y2[t] = fmaxf(acc, 0.f);
    }
    __syncthreads();
    if (t < 2) {
        float acc = lob[t];
        for (int k = 0; k < 128; ++k) acc += y2[k] * low[k * 2 + t];
        out[row * 2 + t] = acc;
    }
}

extern "C" void kernel_launch(void* const* d_in, const int* in_sizes, int n_in,
                              void* d_out, int out_size, void* d_ws, size_t ws_size,
                              hipStream_t stream)
{
    const float* x     = (const float*)d_in[0];
    const float* ts    = (const float*)d_in[1];
    const float* tfidf = (const float*)d_in[2];
    const float* Wall  = (const float*)d_in[3];
    const float* ball  = (const float*)d_in[4];
    const float* Uall  = (const float*)d_in[5];
    const float* bu    = (const float*)d_in[6];
    const float* Wd    = (const float*)d_in[7];
    const float* bd    = (const float*)d_in[8];
    const float* fcw   = (const float*)d_in[9];
    const float* fcb   = (const float*)d_in[10];
    const float* l1w   = (const float*)d_in[11];
    const float* l1b   = (const float*)d_in[12];
    const float* l2w   = (const float*)d_in[13];
    const float* l2b   = (const float*)d_in[14];
    const float* low   = (const float*)d_in[15];
    const float* lob   = (const float*)d_in[16];
    float* out = (float*)d_out;

    unsigned* wsu = (unsigned*)d_ws;
    unsigned* h2a = wsu;
    unsigned* h2b = h2a + BB * HH;
    unsigned* c2a = h2b + BB * HH;
    unsigned* c2b = c2a + BB * HH;
    float* hs  = (float*)(c2b + BB * HH);
    float* tsT = hs + BB * HH;
    unsigned* barv = (unsigned*)(tsT + BB * SS);               // 1024 u32
    unsigned short* B1 = (unsigned short*)(barv + 1024);
    unsigned short* B2 = B1 + (size_t)32 * 32 * 4 * 2 * 64 * 8;   // B1 = 8.4MB
    unsigned* xpk = (unsigned*)(B2 + (size_t)32 * 16 * 2 * 64 * 8); // after 1MB B2
    const size_t need = ((char*)(xpk + (size_t)BB * SS * EE)) - (char*)d_ws;
    const int use_xp = (ws_size >= need) ? 1 : 0;

    prep_split<<<1152, 256, 0, stream>>>(Wall, Uall, Wd, B1, B2);
    if (use_xp)
        prep_pack<<<65536, 256, 0, stream>>>(x, xpk);

    void* args[] = { (void*)&x, (void*)&xpk, (void*)&use_xp, (void*)&ts,
                     (void*)&ball, (void*)&bu, (void*)&bd,
                     (void*)&B1, (void*)&B2,
                     (void*)&h2a, (void*)&h2b, (void*)&c2a, (void*)&c2b,
                     (void*)&hs, (void*)&tsT, (void*)&barv };
    hipLaunchCooperativeKernel((void*)lstm_persistent, dim3(256), dim3(512), args, 0, stream);

    tail_kernel<<<256, 256, 0, stream>>>(tfidf, hs, fcw, fcb, l1w, l1b, l2w, l2b,
                                         low, lob, out);
}

// Round 19
// 4212.251 us; speedup vs baseline: 1.7677x; 1.1824x over previous
//
#include <hip/hip_runtime.h>
#include <hip/hip_cooperative_groups.h>

namespace cg = cooperative_groups;

#define BB 256
#define SS 512
#define EE 512
#define HH 512
#define G4 2048
#define NTF 799

typedef __attribute__((ext_vector_type(8))) short bf16x8;
typedef __attribute__((ext_vector_type(4))) float f32x4;

#define MF(a, b, c) __builtin_amdgcn_mfma_f32_16x16x32_bf16((a), (b), (c), 0, 0, 0)

__device__ __forceinline__ float my_sig(float v) { return 1.0f / (1.0f + __expf(-v)); }
__device__ __forceinline__ float my_tanh(float v) { float e = __expf(2.0f * v); return 1.0f - 2.0f / (e + 1.0f); }

__device__ __forceinline__ unsigned short f2bf(float f) {   // RNE fp32->bf16
    unsigned u = __builtin_bit_cast(unsigned, f);
    u = (u + 0x7FFFu + ((u >> 16) & 1u)) >> 16;
    return (unsigned short)u;
}
__device__ __forceinline__ float bf2f(unsigned short h) {
    unsigned u = ((unsigned)h) << 16;
    return __builtin_bit_cast(float, u);
}
__device__ __forceinline__ unsigned packsplit(float f) {
    unsigned short hi = f2bf(f);
    unsigned short lo = f2bf(f - bf2f(hi));
    return ((unsigned)hi << 16) | (unsigned)lo;
}
__device__ __forceinline__ bf16x8 unhi(uint4 a, uint4 b) {
    union { unsigned u[4]; bf16x8 v; } r;
    r.u[0] = __builtin_amdgcn_perm(a.y, a.x, 0x07060302u);
    r.u[1] = __builtin_amdgcn_perm(a.w, a.z, 0x07060302u);
    r.u[2] = __builtin_amdgcn_perm(b.y, b.x, 0x07060302u);
    r.u[3] = __builtin_amdgcn_perm(b.w, b.z, 0x07060302u);
    return r.v;
}
__device__ __forceinline__ bf16x8 unlo(uint4 a, uint4 b) {
    union { unsigned u[4]; bf16x8 v; } r;
    r.u[0] = __builtin_amdgcn_perm(a.y, a.x, 0x05040100u);
    r.u[1] = __builtin_amdgcn_perm(a.w, a.z, 0x05040100u);
    r.u[2] = __builtin_amdgcn_perm(b.y, b.x, 0x05040100u);
    r.u[3] = __builtin_amdgcn_perm(b.w, b.z, 0x05040100u);
    return r.v;
}

// sc1 coherent / plain cached asm loads (verified r4-r18)
__device__ __forceinline__ void ld4_sc1(uint4& d, const unsigned* p) {
    asm volatile("global_load_dwordx4 %0, %1, off sc0 sc1" : "=v"(d) : "v"(p));
}
__device__ __forceinline__ void ld4_c(uint4& d, const unsigned* p) {
    asm volatile("global_load_dwordx4 %0, %1, off" : "=v"(d) : "v"(p));
}
__device__ __forceinline__ void st_devu(unsigned* p, unsigned v) {
    __hip_atomic_store(p, v, __ATOMIC_RELAXED, __HIP_MEMORY_SCOPE_AGENT);
}
__device__ __forceinline__ unsigned ld_devu(const unsigned* p) {
    return __hip_atomic_load(p, __ATOMIC_RELAXED, __HIP_MEMORY_SCOPE_AGENT);
}

// ---------------------------------------------------------------------------
// Prep: split weights into bf16 hi/lo MFMA B-fragments (verbatim r8-r18).
// ---------------------------------------------------------------------------
__global__ void __launch_bounds__(256)
prep_split(const float* __restrict__ Wall, const float* __restrict__ Uall,
           const float* __restrict__ Wd,
           unsigned short* __restrict__ B1, unsigned short* __restrict__ B2)
{
    const int t = blockIdx.x * 256 + threadIdx.x;
    if (t < 262144) {
        const int lane = t & 63, wc = (t >> 6) & 3, kc = (t >> 8) & 31, cgi = t >> 13;
        const int kb = ((kc & 15) << 5) + ((lane >> 4) << 3);
        const int col = (wc << 9) + (cgi << 4) + (lane & 15);
        const float* src = (kc < 16) ? Wall : Uall;
        bf16x8 vh, vl;
#pragma unroll
        for (int j = 0; j < 8; ++j) {
            float f = src[(size_t)(kb + j) * G4 + col];
            unsigned short h16 = f2bf(f);
            vh[j] = (short)h16;
            vl[j] = (short)f2bf(f - bf2f(h16));
        }
        const int g = t >> 6;
        *(bf16x8*)(B1 + ((size_t)(g * 2 + 0) * 64 + lane) * 8) = vh;
        *(bf16x8*)(B1 + ((size_t)(g * 2 + 1) * 64 + lane) * 8) = vl;
    } else if (t < 262144 + 32768) {
        const int u = t - 262144;
        const int lane = u & 63, kch = (u >> 6) & 15, cgi = u >> 10;
        const int kb = (kch << 5) + ((lane >> 4) << 3);
        const int col = (cgi << 4) + (lane & 15);
        bf16x8 vh, vl;
#pragma unroll
        for (int j = 0; j < 8; ++j) {
            float f = Wd[(size_t)(kb + j) * HH + col];
            unsigned short h16 = f2bf(f);
            vh[j] = (short)h16;
            vl[j] = (short)f2bf(f - bf2f(h16));
        }
        const int g = u >> 6;
        *(bf16x8*)(B2 + ((size_t)(g * 2 + 0) * 64 + lane) * 8) = vh;
        *(bf16x8*)(B2 + ((size_t)(g * 2 + 1) * 64 + lane) * 8) = vl;
    }
}

// Prep: pack x -> hi|lo u32 (same layout) so step staging is a pure copy.
__global__ void __launch_bounds__(256)
prep_pack(const float* __restrict__ x, unsigned* __restrict__ xpk)
{
    const size_t i = (size_t)blockIdx.x * 256 + threadIdx.x;   // 16.7M float4s
    float4 v = ((const float4*)x)[i];
    uint4 p;
    p.x = packsplit(v.x); p.y = packsplit(v.y);
    p.z = packsplit(v.z); p.w = packsplit(v.w);
    ((uint4*)xpk)[i] = p;
}

#define B1FRAG(kcv, wcv, term) (*(const bf16x8*)(B1 +                          \
    ((size_t)(((cgi * 32 + (kcv)) * 4 + (wcv)) * 2 + (term)) * 64 + lane) * 8))
#define B2FRAG(kchv, term) (*(const bf16x8*)(B2 +                              \
    ((size_t)((cgi * 16 + (kchv)) * 2 + (term)) * 64 + lane) * 8))

// gate-partial LDS index, bank-hashed (2-way max = free)
#define GPIDX(row, slot, col)                                                  \
    ((row) * 256 + (slot) * 64 + ((col) ^ (((((row) & 3) ^ (((row) >> 2) & 3))) << 4)))

// ---------------------------------------------------------------------------
// Persistent time-LSTM: r18 structure VERBATIM (4.9ms verified); micro-pass:
// s_sleep(1) poll cadence + loop-invariant address/pointer hoisting.
// ---------------------------------------------------------------------------
__global__ void __launch_bounds__(512) __attribute__((amdgpu_waves_per_eu(2)))
lstm_persistent(const float* __restrict__ x, const unsigned* __restrict__ xp,
                const int use_xp, const float* __restrict__ ts,
                const float* __restrict__ ball, const float* __restrict__ bu,
                const float* __restrict__ bd,
                const unsigned short* __restrict__ B1,
                const unsigned short* __restrict__ B2,
                unsigned* __restrict__ h2a, unsigned* __restrict__ h2b,
                unsigned* __restrict__ c2a, unsigned* __restrict__ c2b,
                float* __restrict__ hsum, float* __restrict__ tsT,
                unsigned* __restrict__ barv)
{
    cg::grid_group grid = cg::this_grid();
    const int tid = threadIdx.x;
    const int bid = blockIdx.x;
    const int gtid = (bid << 9) + tid;

    for (int i = gtid; i < BB * HH; i += 131072) { h2a[i] = 0u; c2a[i] = 0u; }
    for (int i = gtid; i < BB * SS; i += 131072) {
        int b = i >> 9, s = i & 511;
        tsT[s * BB + b] = ts[i];
    }
    if (gtid < 1024) barv[gtid] = 0u;
    grid.sync();

    // XCD-aware bijective relabeling (L2 affinity for the 4 cgi slices/XCD)
    const int xcd = bid & 7, tt = bid >> 3;
    const int cgi = (xcd << 2) | (tt & 3);   // 0..31 -> m0
    const int rg  = tt >> 2;                 // 0..7  -> r0 (sync group)
    const int r0  = rg << 5;
    const int m0  = cgi << 4;

    const int wid = tid >> 6, lane = tid & 63;
    const int lrow = lane & 15, lk8 = lane >> 4;
    const int kq = wid & 3, ch = wid >> 2;
    const int srow = tid >> 4, scb = tid & 15;
    const int rl = srow, mj = scb;

    __shared__ __align__(16) unsigned R1[32 * 512];  // AX -> AC
    __shared__ __align__(16) unsigned R2[32 * 512];  // AH -> partials
    uint4* R1v = (uint4*)R1;
    uint4* R2v = (uint4*)R2;
    float* gp  = (float*)R2;              // [32][4][64] hashed, 32KB
    float* gp2 = (float*)(R2 + 8192);     // [32][132], 17KB

    unsigned* arr = barv;                 // per-rg counter at barv[rg*64]
    const int myline = rg << 6;

    // register-resident: W frags + Wd frags
    bf16x8 wfh[4][2], wfl[4][2], d2h[2], d2l[2];
#pragma unroll
    for (int q = 0; q < 4; ++q)
#pragma unroll
        for (int wcl = 0; wcl < 2; ++wcl) {
            wfh[q][wcl] = B1FRAG((kq << 2) + q, (ch << 1) + wcl, 0);
            wfl[q][wcl] = B1FRAG((kq << 2) + q, (ch << 1) + wcl, 1);
        }
#pragma unroll
    for (int e = 0; e < 2; ++e) {
        d2h[e] = B2FRAG((wid << 1) + e, 0);
        d2l[e] = B2FRAG((wid << 1) + e, 1);
    }

    float bias4[4];
#pragma unroll
    for (int k = 0; k < 4; ++k)
        bias4[k] = ball[(k << 9) + m0 + mj] + bu[(k << 9) + m0 + mj];
    const float bias2v = bd[m0 + mj];

    // ---- hoisted loop-invariant addressing ----
    // staging LDS slots (uint4 index) and global row bases
    int stg_slot[8];
#pragma unroll
    for (int j = 0; j < 8; ++j)
        stg_slot[j] = srow * 128 + ((scb + (j << 4)) ^ (srow & 7));
    const size_t xrowoff = (size_t)(r0 + srow) * (SS * EE);
    const int hrowoff = (r0 + srow) * HH;
    // MFMA LDS read slots (uint4 index): [q][wr] pair base
    int rd_a[4][2], rd_b2[2][2];
#pragma unroll
    for (int q = 0; q < 4; ++q)
#pragma unroll
        for (int wr = 0; wr < 2; ++wr) {
            const int row_ = (wr << 4) | lrow;
            const int cb_ = (((kq << 2) + q) << 3) + (lk8 << 1);
            rd_a[q][wr] = row_ * 128 + (cb_ ^ (row_ & 7));
        }
#pragma unroll
    for (int e = 0; e < 2; ++e)
#pragma unroll
        for (int wr = 0; wr < 2; ++wr) {
            const int row_ = (wr << 4) | lrow;
            const int cb_ = (((wid << 1) + e) << 3) + (lk8 << 1);
            rd_b2[e][wr] = row_ * 128 + (cb_ ^ (row_ & 7));
        }
    // second element of each pair (cb_+1 swizzled)
    int rd_a1[4][2], rd_b21[2][2];
#pragma unroll
    for (int q = 0; q < 4; ++q)
#pragma unroll
        for (int wr = 0; wr < 2; ++wr) {
            const int row_ = (wr << 4) | lrow;
            const int cb_ = (((kq << 2) + q) << 3) + (lk8 << 1);
            rd_a1[q][wr] = row_ * 128 + ((cb_ + 1) ^ (row_ & 7));
        }
#pragma unroll
    for (int e = 0; e < 2; ++e)
#pragma unroll
        for (int wr = 0; wr < 2; ++wr) {
            const int row_ = (wr << 4) | lrow;
            const int cb_ = (((wid << 1) + e) << 3) + (lk8 << 1);
            rd_b21[e][wr] = row_ * 128 + ((cb_ + 1) ^ (row_ & 7));
        }
    // partial-write indices
    int wgp[2][2][4], wgp2[2][4];
#pragma unroll
    for (int wr = 0; wr < 2; ++wr)
#pragma unroll
        for (int wcl = 0; wcl < 2; ++wcl)
#pragma unroll
            for (int i = 0; i < 4; ++i)
                wgp[wr][wcl][i] = GPIDX((wr << 4) + (lk8 << 2) + i, kq,
                                        ((ch << 1) + wcl) * 16 + lrow);
#pragma unroll
    for (int wr = 0; wr < 2; ++wr)
#pragma unroll
        for (int i = 0; i < 4; ++i)
            wgp2[wr][i] = ((wr << 4) + (lk8 << 2) + i) * 132 + (wid << 4) + lrow;
    // reduce-read indices
    int rgp[4][4], rgp2[8];
#pragma unroll
    for (int k = 0; k < 4; ++k)
#pragma unroll
        for (int p = 0; p < 4; ++p)
            rgp[k][p] = GPIDX(rl, p, (k << 4) + mj);
#pragma unroll
    for (int p = 0; p < 8; ++p)
        rgp2[p] = rl * 132 + (p << 4) + mj;
    const int gidx = (r0 + rl) * HH + m0 + mj;
    const float* tsbase = tsT + r0 + rl;

    float creg = 0.f, hsreg = 0.f;

#pragma unroll 1
    for (int s = 0; s < SS; ++s) {
        const unsigned* h2p = (s & 1) ? h2b : h2a;
        const unsigned* c2p = (s & 1) ? c2b : c2a;
        unsigned* h2n = (s & 1) ? h2a : h2b;
        unsigned* c2n = (s & 1) ? c2a : c2b;
        const size_t sb = (size_t)s * EE;

        // ---- A: stage AX <- x(s) ----
        __syncthreads();                      // prev-step partial reads done
        if (use_xp) {
            const unsigned* xpp = xp + xrowoff + sb;
            uint4 xv[8];
#pragma unroll
            for (int j = 0; j < 8; ++j) ld4_c(xv[j], xpp + ((scb + (j << 4)) << 2));
            asm volatile("s_waitcnt vmcnt(0)" ::: "memory");
            __builtin_amdgcn_sched_barrier(0);
#pragma unroll
            for (int j = 0; j < 8; ++j) R1v[stg_slot[j]] = xv[j];
        } else {
            const float* xfp = x + xrowoff + sb;
#pragma unroll
            for (int j = 0; j < 8; ++j) {
                float4 v = *(const float4*)(xfp + ((scb + (j << 4)) << 2));
                uint4 pk;
                pk.x = packsplit(v.x); pk.y = packsplit(v.y);
                pk.z = packsplit(v.z); pk.w = packsplit(v.w);
                R1v[stg_slot[j]] = pk;
            }
        }
        __syncthreads();

        // ---- phase A: x.U MFMAs, U frags streamed (double-buffered) ----
        f32x4 acc[2][2];
        acc[0][0] = acc[0][1] = acc[1][0] = acc[1][1] = (f32x4){0.f, 0.f, 0.f, 0.f};
        {
            bf16x8 ufh[2][2], ufl[2][2];
#pragma unroll
            for (int wcl = 0; wcl < 2; ++wcl) {
                ufh[0][wcl] = B1FRAG(16 + (kq << 2), (ch << 1) + wcl, 0);
                ufl[0][wcl] = B1FRAG(16 + (kq << 2), (ch << 1) + wcl, 1);
            }
#pragma unroll
            for (int q = 0; q < 4; ++q) {
                const int cur = q & 1, nxt = cur ^ 1;
                if (q < 3) {
#pragma unroll
                    for (int wcl = 0; wcl < 2; ++wcl) {
                        ufh[nxt][wcl] = B1FRAG(16 + (kq << 2) + q + 1, (ch << 1) + wcl, 0);
                        ufl[nxt][wcl] = B1FRAG(16 + (kq << 2) + q + 1, (ch << 1) + wcl, 1);
                    }
                }
#pragma unroll
                for (int wr = 0; wr < 2; ++wr) {
                    uint4 qa = R1v[rd_a[q][wr]];
                    uint4 qb = R1v[rd_a1[q][wr]];
                    bf16x8 ah = unhi(qa, qb), al = unlo(qa, qb);
#pragma unroll
                    for (int wcl = 0; wcl < 2; ++wcl) {
                        acc[wr][wcl] = MF(ah, ufh[cur][wcl], acc[wr][wcl]);
                        acc[wr][wcl] = MF(ah, ufl[cur][wcl], acc[wr][wcl]);
                        acc[wr][wcl] = MF(al, ufh[cur][wcl], acc[wr][wcl]);
                    }
                }
            }
        }

        // ---- B: per-rg wait (all 32 same-rg blocks finished step s-1) ----
        if (tid == 0) {
            const unsigned tgt = 32u * (unsigned)s;
            while (ld_devu(&arr[myline]) < tgt)
                __builtin_amdgcn_s_sleep(1);
        }
        __syncthreads();
        asm volatile("" ::: "memory");

        // ---- C: fused h+c load (16 dwordx4, vmcnt(8)/vmcnt(0) split) ----
        {
            const unsigned* hp = h2p + hrowoff;
            const unsigned* cp = c2p + hrowoff;
            uint4 hv[8], cv[8];
#pragma unroll
            for (int j = 0; j < 8; ++j) ld4_sc1(hv[j], hp + ((scb + (j << 4)) << 2));
#pragma unroll
            for (int j = 0; j < 8; ++j) ld4_sc1(cv[j], cp + ((scb + (j << 4)) << 2));
            asm volatile("s_waitcnt vmcnt(8)" ::: "memory");
            __builtin_amdgcn_sched_barrier(0);
#pragma unroll
            for (int j = 0; j < 8; ++j) R2v[stg_slot[j]] = hv[j];
            asm volatile("s_waitcnt vmcnt(0)" ::: "memory");
            __builtin_amdgcn_sched_barrier(0);
#pragma unroll
            for (int j = 0; j < 8; ++j) R1v[stg_slot[j]] = cv[j];
        }
        __syncthreads();

        // ---- phase B: h.W MFMAs (resident frags) into same acc; then G2 ----
#pragma unroll
        for (int q = 0; q < 4; ++q) {
#pragma unroll
            for (int wr = 0; wr < 2; ++wr) {
                uint4 qa = R2v[rd_a[q][wr]];
                uint4 qb = R2v[rd_a1[q][wr]];
                bf16x8 ah = unhi(qa, qb), al = unlo(qa, qb);
#pragma unroll
                for (int wcl = 0; wcl < 2; ++wcl) {
                    acc[wr][wcl] = MF(ah, wfh[q][wcl], acc[wr][wcl]);
                    acc[wr][wcl] = MF(ah, wfl[q][wcl], acc[wr][wcl]);
                    acc[wr][wcl] = MF(al, wfh[q][wcl], acc[wr][wcl]);
                }
            }
        }
        f32x4 acc2[2];
        acc2[0] = (f32x4){0.f, 0.f, 0.f, 0.f};
        acc2[1] = (f32x4){0.f, 0.f, 0.f, 0.f};
#pragma unroll
        for (int e = 0; e < 2; ++e) {
#pragma unroll
            for (int wr = 0; wr < 2; ++wr) {
                uint4 qa = R1v[rd_b2[e][wr]];
                uint4 qb = R1v[rd_b21[e][wr]];
                bf16x8 ah = unhi(qa, qb), al = unlo(qa, qb);
                acc2[wr] = MF(ah, d2h[e], acc2[wr]);
                acc2[wr] = MF(ah, d2l[e], acc2[wr]);
                acc2[wr] = MF(al, d2h[e], acc2[wr]);
            }
        }
        __syncthreads();   // AH/AC reads done before partials overwrite R2

        // ---- E: partial writes (gp: slot=kq; gp2: slot=wid) ----
#pragma unroll
        for (int wr = 0; wr < 2; ++wr)
#pragma unroll
            for (int wcl = 0; wcl < 2; ++wcl)
#pragma unroll
                for (int i = 0; i < 4; ++i)
                    gp[wgp[wr][wcl][i]] = acc[wr][wcl][i];
#pragma unroll
        for (int wr = 0; wr < 2; ++wr)
#pragma unroll
            for (int i = 0; i < 4; ++i)
                gp2[wgp2[wr][i]] = acc2[wr][i];
        __syncthreads();

        // ---- F: reduce + update + sc1 stores ----
        {
            float gv[4];
#pragma unroll
            for (int k = 0; k < 4; ++k) {
                float sacc = bias4[k];
#pragma unroll
                for (int p = 0; p < 4; ++p)
                    sacc += gp[rgp[k][p]];
                gv[k] = my_sig(sacc);
            }
            float sacc2 = bias2v;
#pragma unroll
            for (int p = 0; p < 8; ++p)
                sacc2 += gp2[rgp2[p]];
            const float cs1v = my_tanh(sacc2);
            const float tv = tsbase[s * BB];
            const float cadj = creg + cs1v * (tv - 1.0f);
            const float cnew = gv[0] * cadj + gv[1] * gv[3];
            const float hnew = gv[2] * my_tanh(cnew);
            creg = cnew; hsreg += hnew;
            st_devu(&c2n[gidx], packsplit(cnew));
            st_devu(&h2n[gidx], packsplit(hnew));
        }

        // ---- G: drain + per-rg arrival ----
        asm volatile("s_waitcnt vmcnt(0)" ::: "memory");
        __syncthreads();
        if (tid == 0)
            __hip_atomic_fetch_add(&arr[myline], 1u, __ATOMIC_RELAXED,
                                   __HIP_MEMORY_SCOPE_AGENT);
    }

    hsum[gidx] = hsreg;
}

// Tail: sub = relu(tfidf@fcw+b); x = [sub | hsum/512]; 3-layer MLP (fp32).
__global__ void __launch_bounds__(256)
tail_kernel(const float* __restrict__ tfidf, const float* __restrict__ hsum,
            const float* __restrict__ fcw, const float* __restrict__ fcb,
            const float* __restrict__ l1w, const float* __restrict__ l1b,
            const float* __restrict__ l2w, const float* __restrict__ l2b,
            const float* __restrict__ low, const float* __restrict__ lob,
            float* __restrict__ out)
{
    const int row = blockIdx.x;
    const int t = threadIdx.x;
    __shared__ float tf[800];
    __shared__ float xrow[1024];
    __shared__ float y1[256];
    __shared__ float y2[128];

    for (int k = t; k < NTF; k += 256) tf[k] = tfidf[row * NTF + k];
    __syncthreads();

    for (int n = t; n < 512; n += 256) {
        float acc = fcb[n];
        for (int k = 0; k < NTF; ++k) acc += tf[k] * fcw[k * 512 + n];
        xrow[n] = fmaxf(acc, 0.f);
    }
    for (int n = t; n < 512; n += 256)
        xrow[512 + n] = hsum[row * HH + n] * (1.0f / 512.0f);
    __syncthreads();

    {
        float acc = l1b[t];
        for (int k = 0; k < 1024; ++k) acc += xrow[k] * l1w[k * 256 + t];
        y1[t] = fmaxf(acc, 0.f);
    }
    __syncthreads();
    if (t < 128) {
        float acc = l2b[t];
        for (int k = 0; k < 256; ++k) acc += y1[k] * l2w[k * 128 + t];
        y2[t] = fmaxf(acc, 0.f);
    }
    __syncthreads();
    if (t < 2) {
        float acc = lob[t];
        for (int k = 0; k < 128; ++k) acc += y2[k] * low[k * 2 + t];
        out[row * 2 + t] = acc;
    }
}

extern "C" void kernel_launch(void* const* d_in, const int* in_sizes, int n_in,
                              void* d_out, int out_size, void* d_ws, size_t ws_size,
                              hipStream_t stream)
{
    const float* x     = (const float*)d_in[0];
    const float* ts    = (const float*)d_in[1];
    const float* tfidf = (const float*)d_in[2];
    const float* Wall  = (const float*)d_in[3];
    const float* ball  = (const float*)d_in[4];
    const float* Uall  = (const float*)d_in[5];
    const float* bu    = (const float*)d_in[6];
    const float* Wd    = (const float*)d_in[7];
    const float* bd    = (const float*)d_in[8];
    const float* fcw   = (const float*)d_in[9];
    const float* fcb   = (const float*)d_in[10];
    const float* l1w   = (const float*)d_in[11];
    const float* l1b   = (const float*)d_in[12];
    const float* l2w   = (const float*)d_in[13];
    const float* l2b   = (const float*)d_in[14];
    const float* low   = (const float*)d_in[15];
    const float* lob   = (const float*)d_in[16];
    float* out = (float*)d_out;

    unsigned* wsu = (unsigned*)d_ws;
    unsigned* h2a = wsu;
    unsigned* h2b = h2a + BB * HH;
    unsigned* c2a = h2b + BB * HH;
    unsigned* c2b = c2a + BB * HH;
    float* hs  = (float*)(c2b + BB * HH);
    float* tsT = hs + BB * HH;
    unsigned* barv = (unsigned*)(tsT + BB * SS);               // 1024 u32
    unsigned short* B1 = (unsigned short*)(barv + 1024);
    unsigned short* B2 = B1 + (size_t)32 * 32 * 4 * 2 * 64 * 8;   // B1 = 8.4MB
    unsigned* xpk = (unsigned*)(B2 + (size_t)32 * 16 * 2 * 64 * 8); // after 1MB B2
    const size_t need = ((char*)(xpk + (size_t)BB * SS * EE)) - (char*)d_ws;
    const int use_xp = (ws_size >= need) ? 1 : 0;

    prep_split<<<1152, 256, 0, stream>>>(Wall, Uall, Wd, B1, B2);
    if (use_xp)
        prep_pack<<<65536, 256, 0, stream>>>(x, xpk);

    void* args[] = { (void*)&x, (void*)&xpk, (void*)&use_xp, (void*)&ts,
                     (void*)&ball, (void*)&bu, (void*)&bd,
                     (void*)&B1, (void*)&B2,
                     (void*)&h2a, (void*)&h2b, (void*)&c2a, (void*)&c2b,
                     (void*)&hs, (void*)&tsT, (void*)&barv };
    hipLaunchCooperativeKernel((void*)lstm_persistent, dim3(256), dim3(512), args, 0, stream);

    tail_kernel<<<256, 256, 0, stream>>>(tfidf, hs, fcw, fcb, l1w, l1b, l2w, l2b,
                                         low, lob, out);
}